// Round 1
// 2351.166 us; speedup vs baseline: 1.9992x; 1.9992x over previous
//
#include <hip/hip_runtime.h>
#include <math.h>

#define B 8
#define CIN 64
#define COUT 64
#define H 512
#define W 512
#define KS 3

// conv tiling: 16x16 output tile, 32 co per block (4 waves x 8 co),
// each thread: 4 pixels (along W) x 8 co = 32 accumulators.
#define TH 16
#define TW 16
#define PX 4
#define CO_T 8
#define CO_B 32
#define CI_BLK 16
#define SROW 19              // padded LDS row stride (odd -> no 4-way bank conflict)
#define STILE (18 * SROW)    // words per ci slice = 342

// ---------------------------------------------------------------------------
// Kernel 1: modulate + demodulate. Writes TRANSPOSED layout wm[b][ci][co][9]
// so the conv kernel's per-ci weight reads are one contiguous scalar burst.
// grid = B*COUT blocks, 64 threads (1 wave); thread ci owns one input channel.
// ---------------------------------------------------------------------------
__global__ __launch_bounds__(64) void modw_kernel(const float* __restrict__ w,
                                                  const float* __restrict__ weight,
                                                  float* __restrict__ wm) {
  int b  = blockIdx.x >> 6;
  int co = blockIdx.x & 63;
  int ci = threadIdx.x;
  const float scale = 1.0f / 24.0f;  // 1/sqrt(CIN*K*K) = 1/sqrt(576)
  float wv = w[b * CIN + ci] * scale;
  const float* wp = weight + ((size_t)co * CIN + ci) * 9;
  float v[9];
  float ss = 0.f;
#pragma unroll
  for (int j = 0; j < 9; j++) {
    v[j] = wp[j] * wv;
    ss = fmaf(v[j], v[j], ss);
  }
#pragma unroll
  for (int off = 32; off > 0; off >>= 1) ss += __shfl_xor(ss, off, 64);
  float d = 1.0f / sqrtf(ss + 1e-8f);
  // transposed: [b][ci][co][9]
  float* op = wm + (((size_t)b * CIN + ci) * COUT + co) * 9;
#pragma unroll
  for (int j = 0; j < 9; j++) op[j] = v[j] * d;
}

// ---------------------------------------------------------------------------
// Kernel 2: direct conv. Block = 16x16 output tile, 32 co (4 waves x 8 co).
// Thread layout within a wave: lane = ty*4 + tx; tx owns 4 consecutive W
// pixels, so each weight word feeds 4 FMAs and only 9 uniform scalars are
// live at a time (s_load -> SGPR operands to v_fmac).
// ---------------------------------------------------------------------------
__global__ __launch_bounds__(256, 4) void conv_kernel(const float* __restrict__ x,
                                                      const float* __restrict__ wm,
                                                      float* __restrict__ y) {
  const int bx = blockIdx.x;           // W tile
  const int by = blockIdx.y;           // H tile
  const int bz = blockIdx.z;           // b * 2 + co_group
  const int b   = bz >> 1;
  const int co0 = (bz & 1) * CO_B;

  const int tid  = threadIdx.x;
  // wave id forced to SGPR so the per-wave co-set is provably uniform
  const int wv   = __builtin_amdgcn_readfirstlane(tid >> 6);  // 0..3
  const int lane = tid & 63;
  const int tx   = lane & 3;           // 0..3 -> output cols 4*tx .. 4*tx+3
  const int ty   = lane >> 2;          // 0..15 -> output row

  const int x0 = bx * TW;
  const int y0 = by * TH;
  const int co_w = co0 + wv * CO_T;    // this wave's first co

  __shared__ float sx[CI_BLK * STILE];

  float acc[CO_T][PX];
#pragma unroll
  for (int c = 0; c < CO_T; c++)
#pragma unroll
    for (int p = 0; p < PX; p++) acc[c][p] = 0.f;

  const float* xb = x + (size_t)b * CIN * H * W;

  for (int ci0 = 0; ci0 < CIN; ci0 += CI_BLK) {
    __syncthreads();
    // ---- stage 18x18 halo tile for CI_BLK channels (padded stride 19) ----
    for (int idx = tid; idx < CI_BLK * 18 * 18; idx += 256) {
      int ci  = idx / 324;
      int rem = idx - ci * 324;
      int yy  = rem / 18;
      int xx  = rem - yy * 18;
      int gy = y0 + yy - 1;
      int gx = x0 + xx - 1;
      float v = 0.f;
      if ((unsigned)gy < (unsigned)H && (unsigned)gx < (unsigned)W)
        v = xb[((size_t)(ci0 + ci) * H + gy) * W + gx];
      sx[ci * STILE + yy * SROW + xx] = v;
    }
    __syncthreads();

    // ---- compute ----
    for (int ci = 0; ci < CI_BLK; ci++) {
      // x window for this thread: 3 halo rows x 6 cols (4 px + 2 halo)
      float xw[3][6];
#pragma unroll
      for (int r = 0; r < 3; r++)
#pragma unroll
        for (int j = 0; j < 6; j++)
          xw[r][j] = sx[ci * STILE + (ty + r) * SROW + 4 * tx + j];

      // uniform weights for this wave's 8 co, contiguous 72 floats
      const float* wp = wm + ((size_t)(b * CIN + ci0 + ci) * COUT + co_w) * 9;
#pragma unroll
      for (int c = 0; c < CO_T; c++) {
        float wgt[9];
#pragma unroll
        for (int j = 0; j < 9; j++) wgt[j] = wp[c * 9 + j];
#pragma unroll
        for (int r = 0; r < 3; r++)
#pragma unroll
          for (int kw = 0; kw < 3; kw++)
#pragma unroll
            for (int p = 0; p < PX; p++)
              acc[c][p] = fmaf(xw[r][p + kw], wgt[r * 3 + kw], acc[c][p]);
      }
    }
  }

  // ---- write out: one float4 (4 consecutive pixels) per co ----
#pragma unroll
  for (int c = 0; c < CO_T; c++) {
    float4 v = make_float4(acc[c][0], acc[c][1], acc[c][2], acc[c][3]);
    size_t o = (((size_t)b * COUT + co_w + c) * H + (y0 + ty)) * W + x0 + 4 * tx;
    *reinterpret_cast<float4*>(y + o) = v;
  }
}

extern "C" void kernel_launch(void* const* d_in, const int* in_sizes, int n_in,
                              void* d_out, int out_size, void* d_ws, size_t ws_size,
                              hipStream_t stream) {
  const float* x      = (const float*)d_in[0];   // [B, CIN, H, W]
  const float* w      = (const float*)d_in[1];   // [B, CIN]
  const float* weight = (const float*)d_in[2];   // [COUT, CIN, 3, 3]
  float* y  = (float*)d_out;                     // [B, COUT, H, W]
  float* wm = (float*)d_ws;                      // B*CIN*COUT*9 floats = 1.18 MB

  modw_kernel<<<B * COUT, 64, 0, stream>>>(w, weight, wm);

  dim3 grid(W / TW, H / TH, B * (COUT / CO_B));
  conv_kernel<<<grid, 256, 0, stream>>>(x, wm, y);
}

// Round 2
// 2124.365 us; speedup vs baseline: 2.2126x; 1.1068x over previous
//
#include <hip/hip_runtime.h>
#include <math.h>

#define B 8
#define CIN 64
#define COUT 64
#define H 512
#define W 512
#define HW (H * W)

// conv tiling: 16(rows) x 32(cols) output tile, 32 co per block (4 waves x 8 co),
// each thread: 8 consecutive W-pixels x 8 co = 64 accumulators.
#define TH 16
#define TW 32
#define PX 8
#define CO_T 8
#define CO_B 32
#define CI_BLK 8
#define SROW 35              // 34 cols + 1 pad; 35 mod 32 = 3 -> bank spread
#define STILE (18 * SROW)    // 630 words per ci slice
#define NPOS (18 * 34)       // 612 distinct staging positions

// ---------------------------------------------------------------------------
// Kernel 1: modulate + demodulate. Writes TRANSPOSED layout wm[b][ci][co][9]
// so the conv kernel's per-ci weight reads are one contiguous scalar burst.
// ---------------------------------------------------------------------------
__global__ __launch_bounds__(64) void modw_kernel(const float* __restrict__ w,
                                                  const float* __restrict__ weight,
                                                  float* __restrict__ wm) {
  int b  = blockIdx.x >> 6;
  int co = blockIdx.x & 63;
  int ci = threadIdx.x;
  const float scale = 1.0f / 24.0f;  // 1/sqrt(CIN*K*K) = 1/sqrt(576)
  float wv = w[b * CIN + ci] * scale;
  const float* wp = weight + ((size_t)co * CIN + ci) * 9;
  float v[9];
  float ss = 0.f;
#pragma unroll
  for (int j = 0; j < 9; j++) {
    v[j] = wp[j] * wv;
    ss = fmaf(v[j], v[j], ss);
  }
#pragma unroll
  for (int off = 32; off > 0; off >>= 1) ss += __shfl_xor(ss, off, 64);
  float d = 1.0f / sqrtf(ss + 1e-8f);
  float* op = wm + (((size_t)b * CIN + ci) * COUT + co) * 9;
#pragma unroll
  for (int j = 0; j < 9; j++) op[j] = v[j] * d;
}

// ---------------------------------------------------------------------------
// Kernel 2: direct conv. Block = 16x32 tile, 32 co (4 waves x 8 co).
// Lane map: ty = lane&15 (row), tx = lane>>4 (8-pixel column group).
// LDS read bank = (35*ty + 8*tx) mod 32 -> ~2 lanes/bank (free on CDNA4).
// Weights are wave-uniform -> s_load to SGPRs; each weight feeds 8 FMAs.
// ---------------------------------------------------------------------------
__global__ __launch_bounds__(256) void conv_kernel(const float* __restrict__ x,
                                                   const float* __restrict__ wm,
                                                   float* __restrict__ y) {
  const int bx = blockIdx.x;           // W tile (0..15)
  const int by = blockIdx.y;           // H tile (0..31)
  const int bz = blockIdx.z;           // b * 2 + co_group
  const int b   = bz >> 1;
  const int co0 = (bz & 1) * CO_B;

  const int tid  = threadIdx.x;
  const int wv   = __builtin_amdgcn_readfirstlane(tid >> 6);  // 0..3, uniform
  const int lane = tid & 63;
  const int ty   = lane & 15;          // output row within tile
  const int tx   = lane >> 4;          // 0..3 -> cols 8*tx .. 8*tx+7

  const int x0 = bx * TW;
  const int y0 = by * TH;
  const int co_w = co0 + wv * CO_T;

  __shared__ float sx[CI_BLK * STILE];

  float acc[CO_T][PX];
#pragma unroll
  for (int c = 0; c < CO_T; c++)
#pragma unroll
    for (int p = 0; p < PX; p++) acc[c][p] = 0.f;

  const float* xb = x + (size_t)b * CIN * HW;

  // ---- precompute staging slots (3 per thread, no div/mod in the loop) ----
  int  lofs[3];      // LDS word offset within a ci slice
  long goff[3];      // global offset (gy*W + gx), 0 if OOB
  int  wr[3];        // 1 = this slot writes LDS
  int  ld[3];        // 1 = this slot loads from global (in-bounds)
#pragma unroll
  for (int s = 0; s < 3; s++) {
    int idx = tid + 256 * s;
    int a   = idx < NPOS;
    int yy  = idx / 34;
    int xx  = idx - yy * 34;
    int gy  = y0 + yy - 1;
    int gx  = x0 + xx - 1;
    int inb = a && ((unsigned)gy < (unsigned)H) && ((unsigned)gx < (unsigned)W);
    wr[s]   = a;
    ld[s]   = inb;
    lofs[s] = yy * SROW + xx;
    goff[s] = inb ? ((long)gy * W + gx) : 0;
  }

  for (int ci0 = 0; ci0 < CIN; ci0 += CI_BLK) {
    __syncthreads();
    // ---- stage CI_BLK channels of the 18x34 halo tile ----
#pragma unroll
    for (int s = 0; s < 3; s++) {
      if (wr[s]) {
        const float* base = xb + (size_t)ci0 * HW + goff[s];
#pragma unroll
        for (int ci = 0; ci < CI_BLK; ci++) {
          float v = ld[s] ? base[(size_t)ci * HW] : 0.f;
          sx[ci * STILE + lofs[s]] = v;
        }
      }
    }
    __syncthreads();

    // ---- compute: row-streamed, 576 FMAs per ci on 30 LDS words ----
#pragma unroll 1
    for (int ci = 0; ci < CI_BLK; ci++) {
      const float* wp = wm + ((size_t)(b * CIN + ci0 + ci) * COUT + co_w) * 9;
      const float* sb = sx + ci * STILE + ty * SROW + tx * PX;
#pragma unroll
      for (int r = 0; r < 3; r++) {
        float xr[PX + 2];
#pragma unroll
        for (int j = 0; j < PX + 2; j++) xr[j] = sb[r * SROW + j];
#pragma unroll
        for (int c = 0; c < CO_T; c++) {
#pragma unroll
          for (int kw = 0; kw < 3; kw++) {
            float wgt = wp[c * 9 + r * 3 + kw];
#pragma unroll
            for (int p = 0; p < PX; p++)
              acc[c][p] = fmaf(xr[p + kw], wgt, acc[c][p]);
          }
        }
      }
    }
  }

  // ---- write out: two float4 per co (8 consecutive pixels) ----
#pragma unroll
  for (int c = 0; c < CO_T; c++) {
    size_t o = (((size_t)(b * COUT + co_w + c)) * H + (y0 + ty)) * W + x0 + tx * PX;
    float4 v0 = make_float4(acc[c][0], acc[c][1], acc[c][2], acc[c][3]);
    float4 v1 = make_float4(acc[c][4], acc[c][5], acc[c][6], acc[c][7]);
    *reinterpret_cast<float4*>(y + o)     = v0;
    *reinterpret_cast<float4*>(y + o + 4) = v1;
  }
}

extern "C" void kernel_launch(void* const* d_in, const int* in_sizes, int n_in,
                              void* d_out, int out_size, void* d_ws, size_t ws_size,
                              hipStream_t stream) {
  const float* x      = (const float*)d_in[0];   // [B, CIN, H, W]
  const float* w      = (const float*)d_in[1];   // [B, CIN]
  const float* weight = (const float*)d_in[2];   // [COUT, CIN, 3, 3]
  float* y  = (float*)d_out;                     // [B, COUT, H, W]
  float* wm = (float*)d_ws;                      // B*CIN*COUT*9 floats = 1.18 MB

  modw_kernel<<<B * COUT, 64, 0, stream>>>(w, weight, wm);

  dim3 grid(W / TW, H / TH, B * (COUT / CO_B));
  conv_kernel<<<grid, 256, 0, stream>>>(x, wm, y);
}